// Round 10
// baseline (2791.164 us; speedup 1.0000x reference)
//
#include <hip/hip_runtime.h>
#include <hip/hip_bf16.h>

typedef _Float16 half8 __attribute__((ext_vector_type(8)));
typedef _Float16 h2 __attribute__((ext_vector_type(2)));
typedef float floatx4 __attribute__((ext_vector_type(4)));
typedef unsigned int uint;

typedef __attribute__((address_space(3))) void lds_t;
typedef __attribute__((address_space(1))) void gbl_t;

__device__ __forceinline__ void gload16(const void* g, void* l) {
  __builtin_amdgcn_global_load_lds((gbl_t*)g, (lds_t*)l, 16, 0, 0);
}

#define FENCE() asm volatile("" ::: "memory")

#if __has_builtin(__builtin_amdgcn_perm)
#define PERM(a, b, s) __builtin_amdgcn_perm((a), (b), (s))
#else
__device__ __forceinline__ uint PERM(uint a, uint b, uint s) {
  unsigned long long comb = ((unsigned long long)a << 32) | b;
  uint r = 0;
#pragma unroll
  for (int i = 0; i < 4; ++i) {
    uint idx = (s >> (8 * i)) & 0xFF;
    uint by = (idx < 8) ? (uint)((comb >> (8 * idx)) & 0xFF) : 0u;
    r |= by << (8 * i);
  }
  return r;
}
#endif

// NF4 levels as f16 bit patterns (round-to-nearest), split lo/hi bytes.
// n:  0     1     2     3     4     5     6     7     8     9    10    11    12    13    14    15
//   BC00  B992  B833  B652  B48D  B1EA  ADD4  0000  2D18  3126  33E0  3568  370D  3880  39C9  3C00
#define TL0 0x52339200u
#define TL1 0x00D4EA8Du
#define TL2 0x68E02618u
#define TL3 0x00C9800Du
#define TH0 0xB6B8B9BCu
#define TH1 0x00ADB1B4u
#define TH2 0x3533312Du
#define TH3 0x3C393837u

// dequant 4 codes (selector s = 4 nibble indices, one per byte) -> 2 dwords
// (4 f16 in order), scaled by sc2 (f16 pair).
__device__ __forceinline__ void deq4(uint s, uint sc2, uint& r0, uint& r1) {
  uint s7 = s & 0x07070707u;
  uint m = s & 0x08080808u;
  uint m8 = (m << 5) - (m >> 3);  // 0xFF per byte where nibble>=8
  uint lo = (PERM(TL3, TL2, s7) & m8) | (PERM(TL1, TL0, s) & ~m8);
  uint hi = (PERM(TH3, TH2, s7) & m8) | (PERM(TH1, TH0, s) & ~m8);
  uint a0 = PERM(hi, lo, 0x05010400u);  // [lo0,hi0,lo1,hi1] = f16 c0,c1
  uint a1 = PERM(hi, lo, 0x07030602u);  // f16 c2,c3
  h2 v0 = __builtin_bit_cast(h2, a0) * __builtin_bit_cast(h2, sc2);
  h2 v1 = __builtin_bit_cast(h2, a1) * __builtin_bit_cast(h2, sc2);
  r0 = __builtin_bit_cast(uint, v0);
  r1 = __builtin_bit_cast(uint, v1);
}

// dequant one packed dword (8 codes = cols 8i..8i+7) -> 4 dwords (8 f16 in col order)
__device__ __forceinline__ void deq8(uint d, uint sc2, uint* o) {
  uint e = d & 0x0F0F0F0Fu;
  uint od = (d >> 4) & 0x0F0F0F0Fu;
  uint sA = PERM(od, e, 0x05010400u);  // nibbles c0,c1,c2,c3
  uint sB = PERM(od, e, 0x07030602u);  // c4..c7
  deq4(sA, sc2, o[0], o[1]);
  deq4(sB, sc2, o[2], o[3]);
}

// ---------------- x f32 -> f16 ----------------
__global__ void cvt_f32_to_f16(const float* __restrict__ in,
                               _Float16* __restrict__ out, int total8) {
  int stride = gridDim.x * blockDim.x;
  for (int i = blockIdx.x * blockDim.x + threadIdx.x; i < total8; i += stride) {
    long e = (long)i * 8;
    const float4* ip = reinterpret_cast<const float4*>(in + e);
    float4 a = ip[0], b = ip[1];
    half8 o;
    o[0] = (_Float16)a.x; o[1] = (_Float16)a.y;
    o[2] = (_Float16)a.z; o[3] = (_Float16)a.w;
    o[4] = (_Float16)b.x; o[5] = (_Float16)b.y;
    o[6] = (_Float16)b.z; o[7] = (_Float16)b.w;
    *reinterpret_cast<half8*>(out + e) = o;
  }
}

// ---------------- pack codes: int32 [R][C] -> nibbles [C/64][R][32B] ----------
__global__ void pack_nf4(const int* __restrict__ codes,
                         unsigned char* __restrict__ pk, int R, int C) {
  const int CT = C >> 4;  // 16-code groups per row
  const long total = (long)R * CT;
  const long stride = (long)gridDim.x * blockDim.x;
  for (long i = blockIdx.x * blockDim.x + threadIdx.x; i < total; i += stride) {
    int r = (int)(i / CT);
    int g = (int)(i - (long)r * CT);
    int c0 = g << 4;
    const int4* p = reinterpret_cast<const int4*>(codes + (long)r * C + c0);
    int4 a = p[0], b = p[1], c = p[2], d = p[3];
    uint w0 = (uint)(a.x & 15) | ((uint)(a.y & 15) << 4) |
              ((uint)(a.z & 15) << 8) | ((uint)(a.w & 15) << 12) |
              ((uint)(b.x & 15) << 16) | ((uint)(b.y & 15) << 20) |
              ((uint)(b.z & 15) << 24) | ((uint)(b.w & 15) << 28);
    uint w1 = (uint)(c.x & 15) | ((uint)(c.y & 15) << 4) |
              ((uint)(c.z & 15) << 8) | ((uint)(c.w & 15) << 12) |
              ((uint)(d.x & 15) << 16) | ((uint)(d.y & 15) << 20) |
              ((uint)(d.z & 15) << 24) | ((uint)(d.w & 15) << 28);
    int kt = c0 >> 6;
    long off = ((long)kt * R + r) * 32 + ((c0 & 63) >> 1);
    uint2 v; v.x = w0; v.y = w1;
    *reinterpret_cast<uint2*>(pk + off) = v;
  }
}

// ---------------- pack scales: [R][CB] f32 -> [CB][R] f32 ----------------
__global__ void pack_scales(const float* __restrict__ s,
                            float* __restrict__ o, int R, int CB) {
  const long total = (long)R * CB;
  const long stride = (long)gridDim.x * blockDim.x;
  for (long i = blockIdx.x * blockDim.x + threadIdx.x; i < total; i += stride) {
    int r = (int)(i / CB);
    int cb = (int)(i - (long)r * CB);
    o[(long)cb * R + r] = s[i];
  }
}

// =====================================================================
// 256x256 GEMM, BK=64, 8 waves (2Mx4N), per-wave 128x64 output.
// A: f16, staged via global_load_lds (R7 path, chunk-XOR swizzle, 0 confl).
// B: packed NF4 nibbles [K/64][N][32B] + scales [K/64][N] f32; each thread
// loads 16B packed (= row t>>1, kk-half t&1, 32 codes) + 1 scale to REGS at
// P0(t) for tile t+1, dequants at P2(t) (v_perm LUT, ~124 VALU) and writes
// 4x ds_write_b128 into the swizzled f16 B slabs of sbuf. Staged bytes per
// K-tile: A 32KB + Bpk 8KB + sc 1KB = 41KB (was 64KB) -> attacks the
// measured supply ceiling (~11 B/cy/CU, R4-R9 plateau).
// Certification: P3-end `vmcnt(0) lgkmcnt(0)` (A gloads + dequant writes);
// pk/sc reg loads are compiler-tracked. WAR safety: sbuf A written from
// P0(t) (after t-1's last sbuf read at P3(t-1) barrier); sbuf B written
// P2(t); sbuf readers start P0(t+1) after the certifying barrier.
// EPI: 0 = f16 store; 1 = GH[idx]=silu(GH[idx])*acc (in-place); 2 = f32.
// =====================================================================
template <int K, int N, int EPI>
__global__ __launch_bounds__(512, 2) void gemm256(
    const _Float16* __restrict__ A,
    const unsigned char* __restrict__ BPK,
    const float* __restrict__ BSC,
    _Float16* __restrict__ GH,
    float* __restrict__ OUT) {
  constexpr int NT = K / 64;
  constexpr int NBC = N / 256;
  constexpr int NWG = (8192 / 256) * NBC;
  __shared__ __align__(16) _Float16 lds[2 * 32768];  // 128 KB

  const int t = threadIdx.x;       // 0..511
  const int lane = t & 63;
  const int wave = t >> 6;
  const int wm = wave >> 2;        // 0..1
  const int wn = wave & 3;         // 0..3

  // XCD-bijective swizzle (NWG % 8 == 0), row-major decode (R7)
  int bid = blockIdx.x;
  bid = (bid & 7) * (NWG >> 3) + (bid >> 3);
  const int bm = bid / NBC, bn = bid % NBC;

  // ---- A staging (linear LDS dest, pre-permuted global src) ----
  const int lc = (t & 3) ^ ((t >> 3) & 3);
  const _Float16* gA = A + ((long)bm * 256 + (t >> 2)) * K + lc * 8;
  const long rstep = (long)128 * K;
  const int dst = t * 8;  // f16 units

  // ---- B packed addressing ----
  const int brow = t >> 1;   // 0..255 (slab row)
  const int bhalf = t & 1;   // kk half (cols bhalf*32..+31)
  const unsigned char* gPK = BPK + ((long)(bn * 256 + brow)) * 32 + bhalf * 16;
  const float* gSC = BSC + (bn * 256 + brow);
  const int wh = (brow >> 1) & 3;  // h(row) for write swizzle
  _Float16* wbase0 = (_Float16*)lds + 16384 + bhalf * 8192 + brow * 32;

  // ---- fragment read offsets (f16 units within buffer) ----
  const int rA = wm * 128 + (lane & 15);
  const int rB = wn * 64 + (lane & 15);
  const int ckA = ((lane >> 4) ^ ((rA >> 1) & 3)) * 8;  // h(r+16i)==h(r)
  const int ckB = ((lane >> 4) ^ ((rB >> 1) & 3)) * 8;
  const int offA = rA * 32 + ckA;           // + i*512 (+8192 for kk1)
  const int offB = 16384 + rB * 32 + ckB;   // + j*512 (+8192 for kk1)

  uint4 pkv;
  float scv;

  // dequant pkv/scv -> f16 B slabs of buffer `db`
  auto stage_b = [&](int db) {
    _Float16 sh = (_Float16)scv;
    unsigned short us = __builtin_bit_cast(unsigned short, sh);
    uint sc2 = (uint)us * 0x10001u;
    uint w0[4], w1[4], w2[4], w3[4];
    deq8(pkv.x, sc2, w0);
    deq8(pkv.y, sc2, w1);
    deq8(pkv.z, sc2, w2);
    deq8(pkv.w, sc2, w3);
    _Float16* wb = wbase0 + db * 32768;
    *reinterpret_cast<uint4*>(wb + (0 ^ wh) * 8) = *reinterpret_cast<uint4*>(w0);
    *reinterpret_cast<uint4*>(wb + (1 ^ wh) * 8) = *reinterpret_cast<uint4*>(w1);
    *reinterpret_cast<uint4*>(wb + (2 ^ wh) * 8) = *reinterpret_cast<uint4*>(w2);
    *reinterpret_cast<uint4*>(wb + (3 ^ wh) * 8) = *reinterpret_cast<uint4*>(w3);
  };

  // ---- prologue: tile 0 -> buf0 ----
  gload16(gA, (_Float16*)lds + dst);
  gload16(gA + rstep, (_Float16*)lds + dst + 4096);
  gload16(gA + 32, (_Float16*)lds + 8192 + dst);
  gload16(gA + 32 + rstep, (_Float16*)lds + 8192 + dst + 4096);
  FENCE();
  pkv = *reinterpret_cast<const uint4*>(gPK);
  scv = *gSC;
  gA += 64;
  asm volatile("s_waitcnt vmcnt(0)" ::: "memory");  // A(0) in LDS
  stage_b(0);
  asm volatile("s_waitcnt lgkmcnt(0)" ::: "memory");
  __builtin_amdgcn_s_barrier();
  FENCE();

  floatx4 acc[8][4] = {};

  for (int kt = 0; kt < NT; ++kt) {
    const int cb = kt & 1;
    const int sbuf = cb ^ 1;
    const _Float16* lb = (_Float16*)lds + cb * 32768;
    _Float16* sb = (_Float16*)lds + sbuf * 32768;
    const bool st = (kt + 1 < NT);

    half8 a[8], b[2];

    // ---- P0: read a@kk0 x8 + b[0..1]@kk0; issue ALL t+1 staging ----
#pragma unroll
    for (int i = 0; i < 8; ++i)
      a[i] = *reinterpret_cast<const half8*>(&lb[offA + i * 512]);
    b[0] = *reinterpret_cast<const half8*>(&lb[offB]);
    b[1] = *reinterpret_cast<const half8*>(&lb[offB + 512]);
    if (st) {
      gload16(gA, sb + dst);
      gload16(gA + rstep, sb + dst + 4096);
      gload16(gA + 32, sb + 8192 + dst);
      gload16(gA + 32 + rstep, sb + 8192 + dst + 4096);
      FENCE();
      pkv = *reinterpret_cast<const uint4*>(gPK + (long)(kt + 1) * ((long)N * 32));
      scv = gSC[(long)(kt + 1) * N];
      gA += 64;
    }
    __builtin_amdgcn_s_barrier();
    FENCE();
    __builtin_amdgcn_s_setprio(1);
#pragma unroll
    for (int i = 0; i < 8; ++i) {
      acc[i][0] = __builtin_amdgcn_mfma_f32_16x16x32_f16(a[i], b[0], acc[i][0], 0, 0, 0);
      acc[i][1] = __builtin_amdgcn_mfma_f32_16x16x32_f16(a[i], b[1], acc[i][1], 0, 0, 0);
    }
    __builtin_amdgcn_s_setprio(0);
    __builtin_amdgcn_s_barrier();
    FENCE();

    // ---- P1: read b[2..3]@kk0 ----
    b[0] = *reinterpret_cast<const half8*>(&lb[offB + 2 * 512]);
    b[1] = *reinterpret_cast<const half8*>(&lb[offB + 3 * 512]);
    __builtin_amdgcn_s_barrier();
    FENCE();
    __builtin_amdgcn_s_setprio(1);
#pragma unroll
    for (int i = 0; i < 8; ++i) {
      acc[i][2] = __builtin_amdgcn_mfma_f32_16x16x32_f16(a[i], b[0], acc[i][2], 0, 0, 0);
      acc[i][3] = __builtin_amdgcn_mfma_f32_16x16x32_f16(a[i], b[1], acc[i][3], 0, 0, 0);
    }
    __builtin_amdgcn_s_setprio(0);
    __builtin_amdgcn_s_barrier();
    FENCE();

    // ---- P2: read a@kk1 x8 + b[0..1]@kk1; dequant B(t+1) -> sbuf ----
#pragma unroll
    for (int i = 0; i < 8; ++i)
      a[i] = *reinterpret_cast<const half8*>(&lb[8192 + offA + i * 512]);
    b[0] = *reinterpret_cast<const half8*>(&lb[8192 + offB]);
    b[1] = *reinterpret_cast<const half8*>(&lb[8192 + offB + 512]);
    if (st) { stage_b(sbuf); }
    __builtin_amdgcn_s_barrier();
    FENCE();
    __builtin_amdgcn_s_setprio(1);
#pragma unroll
    for (int i = 0; i < 8; ++i) {
      acc[i][0] = __builtin_amdgcn_mfma_f32_16x16x32_f16(a[i], b[0], acc[i][0], 0, 0, 0);
      acc[i][1] = __builtin_amdgcn_mfma_f32_16x16x32_f16(a[i], b[1], acc[i][1], 0, 0, 0);
    }
    __builtin_amdgcn_s_setprio(0);
    __builtin_amdgcn_s_barrier();
    FENCE();

    // ---- P3: read b[2..3]@kk1; certify A(t+1)+B-writes ----
    b[0] = *reinterpret_cast<const half8*>(&lb[8192 + offB + 2 * 512]);
    b[1] = *reinterpret_cast<const half8*>(&lb[8192 + offB + 3 * 512]);
    __builtin_amdgcn_s_barrier();
    FENCE();
    __builtin_amdgcn_s_setprio(1);
#pragma unroll
    for (int i = 0; i < 8; ++i) {
      acc[i][2] = __builtin_amdgcn_mfma_f32_16x16x32_f16(a[i], b[0], acc[i][2], 0, 0, 0);
      acc[i][3] = __builtin_amdgcn_mfma_f32_16x16x32_f16(a[i], b[1], acc[i][3], 0, 0, 0);
    }
    __builtin_amdgcn_s_setprio(0);
    asm volatile("s_waitcnt vmcnt(0) lgkmcnt(0)" ::: "memory");
    __builtin_amdgcn_s_barrier();
    FENCE();
  }

  // ---- epilogue (plain stores, R7) ----
  const int r0 = bm * 256 + wm * 128 + (lane >> 4) * 4;
  const int c0 = bn * 256 + wn * 64 + (lane & 15);
#pragma unroll
  for (int i = 0; i < 8; ++i) {
#pragma unroll
    for (int j = 0; j < 4; ++j) {
#pragma unroll
      for (int ii = 0; ii < 4; ++ii) {
        const long idx = (long)(r0 + i * 16 + ii) * N + (c0 + j * 16);
        if (EPI == 0) {
          GH[idx] = (_Float16)acc[i][j][ii];
        } else if (EPI == 1) {
          float u = acc[i][j][ii];
          float g = (float)GH[idx];
          GH[idx] = (_Float16)(g / (1.0f + __expf(-g)) * u);
        } else {
          OUT[idx] = acc[i][j][ii];
        }
      }
    }
  }
}

extern "C" void kernel_launch(void* const* d_in, const int* in_sizes, int n_in,
                              void* d_out, int out_size, void* d_ws, size_t ws_size,
                              hipStream_t stream) {
  const float* x           = (const float*)d_in[0];
  const int*   gate_codes  = (const int*)d_in[1];
  const float* gate_scales = (const float*)d_in[2];
  const int*   up_codes    = (const int*)d_in[3];
  const float* up_scales   = (const float*)d_in[4];
  const int*   down_codes  = (const int*)d_in[5];
  const float* down_scales = (const float*)d_in[6];
  float* out = (float*)d_out;

  const long T = 8192, HD = 4096, M = 11008;

  // ws: x16 67MB | gh 180MB | pkG/pkU/pkD 22.5MB ea | scG/scU/scD 2.8MB ea
  char* ws = (char*)d_ws;
  _Float16* x16 = (_Float16*)ws;                     ws += T * HD * 2;
  _Float16* gh  = (_Float16*)ws;                     ws += T * M * 2;
  unsigned char* pkG = (unsigned char*)ws;           ws += M * HD / 2;
  unsigned char* pkU = (unsigned char*)ws;           ws += M * HD / 2;
  unsigned char* pkD = (unsigned char*)ws;           ws += HD * M / 2;
  float* scG = (float*)ws;                           ws += (HD / 64) * M * 4;
  float* scU = (float*)ws;                           ws += (HD / 64) * M * 4;
  float* scD = (float*)ws;

  cvt_f32_to_f16<<<2048, 256, 0, stream>>>(x, x16, (int)(T * HD / 8));
  pack_nf4<<<2048, 256, 0, stream>>>(gate_codes, pkG, (int)M, (int)HD);
  pack_nf4<<<2048, 256, 0, stream>>>(up_codes, pkU, (int)M, (int)HD);
  pack_nf4<<<2048, 256, 0, stream>>>(down_codes, pkD, (int)HD, (int)M);
  pack_scales<<<2048, 256, 0, stream>>>(gate_scales, scG, (int)M, (int)(HD / 64));
  pack_scales<<<2048, 256, 0, stream>>>(up_scales, scU, (int)M, (int)(HD / 64));
  pack_scales<<<2048, 256, 0, stream>>>(down_scales, scD, (int)HD, (int)(M / 64));

  // gate: gh = x @ Wg^T (f16)
  gemm256<4096, 11008, 0><<<(8192 / 256) * (11008 / 256), 512, 0, stream>>>(
      x16, pkG, scG, gh, nullptr);
  // up + SwiGLU: gh = silu(gh) * (x @ Wu^T)
  gemm256<4096, 11008, 1><<<(8192 / 256) * (11008 / 256), 512, 0, stream>>>(
      x16, pkU, scU, gh, nullptr);
  // down: out = gh @ Wd^T (f32)
  gemm256<11008, 4096, 2><<<(8192 / 256) * (4096 / 256), 512, 0, stream>>>(
      gh, pkD, scD, nullptr, out);
}

// Round 11
// 2381.180 us; speedup vs baseline: 1.1722x; 1.1722x over previous
//
#include <hip/hip_runtime.h>
#include <hip/hip_bf16.h>

typedef _Float16 half8 __attribute__((ext_vector_type(8)));
typedef float floatx4 __attribute__((ext_vector_type(4)));

__device__ __constant__ float NF4_TAB[16] = {
    -1.0f, -0.6961928009986877f, -0.5250730514526367f, -0.39491748809814453f,
    -0.28444138169288635f, -0.18477343022823334f, -0.09105003625154495f, 0.0f,
    0.07958029955625534f, 0.16093020141124725f, 0.24611230194568634f,
    0.33791524171829224f, 0.44070982933044434f, 0.5626170039176941f,
    0.7229568362236023f, 1.0f};

typedef __attribute__((address_space(3))) void lds_t;
typedef __attribute__((address_space(1))) void gbl_t;

__device__ __forceinline__ void gload16(const void* g, void* l) {
  __builtin_amdgcn_global_load_lds((gbl_t*)g, (lds_t*)l, 16, 0, 0);
}

#define FENCE() asm volatile("" ::: "memory")

// ---------------- x f32 -> f16 ----------------
__global__ void cvt_f32_to_f16(const float* __restrict__ in,
                               _Float16* __restrict__ out, int total8) {
  int stride = gridDim.x * blockDim.x;
  for (int i = blockIdx.x * blockDim.x + threadIdx.x; i < total8; i += stride) {
    long e = (long)i * 8;
    const float4* ip = reinterpret_cast<const float4*>(in + e);
    float4 a = ip[0], b = ip[1];
    half8 o;
    o[0] = (_Float16)a.x; o[1] = (_Float16)a.y;
    o[2] = (_Float16)a.z; o[3] = (_Float16)a.w;
    o[4] = (_Float16)b.x; o[5] = (_Float16)b.y;
    o[6] = (_Float16)b.z; o[7] = (_Float16)b.w;
    *reinterpret_cast<half8*>(out + e) = o;
  }
}

// ---------------- NF4 dequant: codes[R,C] + scales[R,C/64] -> f16 [R,C] ----
__global__ void dequant_nf4(const int* __restrict__ codes,
                            const float* __restrict__ scales,
                            _Float16* __restrict__ out,
                            int total8, int C, int CB) {
  __shared__ float lut[16];
  if (threadIdx.x < 16) lut[threadIdx.x] = NF4_TAB[threadIdx.x];
  __syncthreads();
  int stride = gridDim.x * blockDim.x;
  for (int i = blockIdx.x * blockDim.x + threadIdx.x; i < total8; i += stride) {
    long e = (long)i * 8;
    int row = (int)(e / C);
    int col = (int)(e - (long)row * C);
    float sc = scales[row * CB + (col >> 6)];
    const int4* cp = reinterpret_cast<const int4*>(codes + e);
    int4 c0 = cp[0];
    int4 c1 = cp[1];
    half8 o;
    o[0] = (_Float16)(lut[c0.x & 15] * sc);
    o[1] = (_Float16)(lut[c0.y & 15] * sc);
    o[2] = (_Float16)(lut[c0.z & 15] * sc);
    o[3] = (_Float16)(lut[c0.w & 15] * sc);
    o[4] = (_Float16)(lut[c1.x & 15] * sc);
    o[5] = (_Float16)(lut[c1.y & 15] * sc);
    o[6] = (_Float16)(lut[c1.z & 15] * sc);
    o[7] = (_Float16)(lut[c1.w & 15] * sc);
    *reinterpret_cast<half8*>(out + e) = o;
  }
}

// =====================================================================
// 256x256 GEMM, BK=32, 8 waves (2Mx4N), per-wave 128x64 output.
// DEEP-RING staging: 4 LDS buffers x 32 KB (A slab 8192 f16 @0, B slab
// 8192 @8192). During tile t, stage tile t+3 into buf (t+3)&3:
//   P0: 2 gloads A(t+3);  P1: 2 gloads B(t+3).
// In-flight: up to 12 loads (3 tiles). ONE counted wait per K-tile at
// P1-end: vmcnt(8) certifies tile t+1 (issued 6 phases = ~3 K-tiles ago,
// covering bandwidth-queued delivery: a tile's 64KB staging drains in
// ~1 K-tile at the measured ~11 B/cy/CU supply; R4-R7's 0.6-1-tile slack
// stalled on this). Tail: kt==NT-3 -> vmcnt(4); kt==NT-2 -> vmcnt(0).
// WAR: buf (t+3)&3 holds tile t-1; its A slab last read P0(t-1), B slab
// P1(t-1); stages at P0(t)/P1(t) are >=2 barriers later.
// Phases: P0 read a[0..3]+b[0..3] (8 rds) -> acc[0..3][*] (16 MFMA);
//         P1 read a[4..7] (4 rds)         -> acc[4..7][*] (16 MFMA).
// Chunk-XOR swizzle (phys chunk = logical ^ ((row>>1)&3)): 0 conflicts
// (verified R3-R7). Linear gload_lds dest + pre-permuted global src.
// EPI: 0 = f16 store; 1 = GH[idx]=silu(GH[idx])*acc (in-place); 2 = f32.
// =====================================================================
template <int K, int N, int EPI>
__global__ __launch_bounds__(512, 2) void gemm256(
    const _Float16* __restrict__ A,
    const _Float16* __restrict__ B,
    _Float16* __restrict__ GH,
    float* __restrict__ OUT) {
  constexpr int NT = K / 32;
  constexpr int NBC = N / 256;
  constexpr int NWG = (8192 / 256) * NBC;
  __shared__ __align__(16) _Float16 lds[4 * 16384];  // 128 KB

  const int t = threadIdx.x;       // 0..511
  const int lane = t & 63;
  const int wave = t >> 6;
  const int wm = wave >> 2;        // 0..1
  const int wn = wave & 3;         // 0..3

  // XCD-bijective swizzle (NWG % 8 == 0 both instantiations), row-major
  int bid = blockIdx.x;
  bid = (bid & 7) * (NWG >> 3) + (bid >> 3);
  const int bm = bid / NBC, bn = bid % NBC;

  // staging: row=(t>>2)(+128), chunk lc=(t&3)^((t>>3)&3) pre-permuted
  const int lc = (t & 3) ^ ((t >> 3) & 3);
  const _Float16* gA = A + ((long)bm * 256 + (t >> 2)) * K + lc * 8;
  const _Float16* gB = B + ((long)bn * 256 + (t >> 2)) * K + lc * 8;
  const long rstep = (long)128 * K;
  const int dst = t * 8;  // f16 units (lane-linear 16B within wave)

  // fragment read offsets (f16 units within a 16384-unit buffer)
  const int rA = wm * 128 + (lane & 15);
  const int rB = wn * 64 + (lane & 15);
  const int ckA = ((lane >> 4) ^ ((rA >> 1) & 3)) * 8;  // h(r+16i)==h(r)
  const int ckB = ((lane >> 4) ^ ((rB >> 1) & 3)) * 8;
  const int offA = rA * 32 + ckA;          // + i*512
  const int offB = 8192 + rB * 32 + ckB;   // + j*512

#define STAGE_A(dbuf) \
  gload16(gA, lds + (dbuf) * 16384 + dst); \
  gload16(gA + rstep, lds + (dbuf) * 16384 + dst + 4096); gA += 32;
#define STAGE_B(dbuf) \
  gload16(gB, lds + (dbuf) * 16384 + 8192 + dst); \
  gload16(gB + rstep, lds + (dbuf) * 16384 + 8192 + dst + 4096); gB += 32;

  // ---- prologue: stage tiles 0,1,2 -> bufs 0,1,2 (12 loads) ----
  STAGE_A(0); STAGE_B(0);
  STAGE_A(1); STAGE_B(1);
  STAGE_A(2); STAGE_B(2);
  asm volatile("s_waitcnt vmcnt(8)" ::: "memory");  // tile 0 landed
  __builtin_amdgcn_s_barrier();
  FENCE();

  floatx4 acc[8][4] = {};

  for (int kt = 0; kt < NT; ++kt) {
    const _Float16* lb = lds + (kt & 3) * 16384;
    const int s3 = (kt + 3) & 3;
    const bool st = (kt + 3 < NT);

    half8 a[4], b[4];

    // ---- P0: read a[0..3] + b[0..3]; stage A(t+3); 16 MFMA rows 0-3 ----
#pragma unroll
    for (int i = 0; i < 4; ++i)
      a[i] = *reinterpret_cast<const half8*>(&lb[offA + i * 512]);
#pragma unroll
    for (int j = 0; j < 4; ++j)
      b[j] = *reinterpret_cast<const half8*>(&lb[offB + j * 512]);
    if (st) { STAGE_A(s3); }
    __builtin_amdgcn_s_barrier();
    FENCE();
    __builtin_amdgcn_s_setprio(1);
#pragma unroll
    for (int i = 0; i < 4; ++i)
#pragma unroll
      for (int j = 0; j < 4; ++j)
        acc[i][j] = __builtin_amdgcn_mfma_f32_16x16x32_f16(a[i], b[j], acc[i][j], 0, 0, 0);
    __builtin_amdgcn_s_setprio(0);
    __builtin_amdgcn_s_barrier();
    FENCE();

    // ---- P1: read a[4..7]; stage B(t+3); certify t+1; 16 MFMA rows 4-7 ----
#pragma unroll
    for (int i = 0; i < 4; ++i)
      a[i] = *reinterpret_cast<const half8*>(&lb[offA + (4 + i) * 512]);
    if (st) { STAGE_B(s3); }
    if (kt < NT - 3)       { asm volatile("s_waitcnt vmcnt(8)" ::: "memory"); }
    else if (kt == NT - 3) { asm volatile("s_waitcnt vmcnt(4)" ::: "memory"); }
    else if (kt == NT - 2) { asm volatile("s_waitcnt vmcnt(0)" ::: "memory"); }
    __builtin_amdgcn_s_barrier();
    FENCE();
    __builtin_amdgcn_s_setprio(1);
#pragma unroll
    for (int i = 0; i < 4; ++i)
#pragma unroll
      for (int j = 0; j < 4; ++j)
        acc[4 + i][j] = __builtin_amdgcn_mfma_f32_16x16x32_f16(a[i], b[j], acc[4 + i][j], 0, 0, 0);
    __builtin_amdgcn_s_setprio(0);
    __builtin_amdgcn_s_barrier();
    FENCE();
  }
#undef STAGE_A
#undef STAGE_B

  // ---- epilogue ----
  const int r0 = bm * 256 + wm * 128 + (lane >> 4) * 4;
  const int c0 = bn * 256 + wn * 64 + (lane & 15);
#pragma unroll
  for (int i = 0; i < 8; ++i) {
#pragma unroll
    for (int j = 0; j < 4; ++j) {
#pragma unroll
      for (int ii = 0; ii < 4; ++ii) {
        const long idx = (long)(r0 + i * 16 + ii) * N + (c0 + j * 16);
        if (EPI == 0) {
          GH[idx] = (_Float16)acc[i][j][ii];
        } else if (EPI == 1) {
          float u = acc[i][j][ii];
          float g = (float)GH[idx];
          GH[idx] = (_Float16)(g / (1.0f + __expf(-g)) * u);
        } else {
          OUT[idx] = acc[i][j][ii];
        }
      }
    }
  }
}

extern "C" void kernel_launch(void* const* d_in, const int* in_sizes, int n_in,
                              void* d_out, int out_size, void* d_ws, size_t ws_size,
                              hipStream_t stream) {
  const float* x           = (const float*)d_in[0];
  const int*   gate_codes  = (const int*)d_in[1];
  const float* gate_scales = (const float*)d_in[2];
  const int*   up_codes    = (const int*)d_in[3];
  const float* up_scales   = (const float*)d_in[4];
  const int*   down_codes  = (const int*)d_in[5];
  const float* down_scales = (const float*)d_in[6];
  float* out = (float*)d_out;

  const long T = 8192, HD = 4096, M = 11008;

  // ws layout (fp16): x16 [T,HD] 67MB | W [M,HD] 90MB (reused 3x) | gh [T,M] 180MB
  char* ws = (char*)d_ws;
  _Float16* x16 = (_Float16*)ws;
  _Float16* W   = (_Float16*)(ws + T * HD * 2);
  _Float16* gh  = (_Float16*)(ws + T * HD * 2 + M * HD * 2);

  cvt_f32_to_f16<<<2048, 256, 0, stream>>>(x, x16, (int)(T * HD / 8));

  // gate: g = x @ Wg^T  -> gh (f16)
  dequant_nf4<<<2048, 256, 0, stream>>>(gate_codes, gate_scales, W,
                                        (int)(M * HD / 8), (int)HD, (int)(HD / 64));
  gemm256<4096, 11008, 0><<<(8192 / 256) * (11008 / 256), 512, 0, stream>>>(
      x16, W, gh, nullptr);

  // up + SwiGLU: gh = silu(gh) * (x @ Wu^T)   (in-place, element-exclusive)
  dequant_nf4<<<2048, 256, 0, stream>>>(up_codes, up_scales, W,
                                        (int)(M * HD / 8), (int)HD, (int)(HD / 64));
  gemm256<4096, 11008, 1><<<(8192 / 256) * (11008 / 256), 512, 0, stream>>>(
      x16, W, gh, nullptr);

  // down: out = gh @ Wd^T  (f32)
  dequant_nf4<<<2048, 256, 0, stream>>>(down_codes, down_scales, W,
                                        (int)(HD * M / 8), (int)M, (int)(M / 64));
  gemm256<11008, 4096, 2><<<(8192 / 256) * (4096 / 256), 512, 0, stream>>>(
      gh, W, nullptr, out);
}

// Round 12
// 2236.847 us; speedup vs baseline: 1.2478x; 1.0645x over previous
//
#include <hip/hip_runtime.h>
#include <hip/hip_bf16.h>

typedef _Float16 half8 __attribute__((ext_vector_type(8)));
typedef float floatx4 __attribute__((ext_vector_type(4)));

__device__ __constant__ float NF4_TAB[16] = {
    -1.0f, -0.6961928009986877f, -0.5250730514526367f, -0.39491748809814453f,
    -0.28444138169288635f, -0.18477343022823334f, -0.09105003625154495f, 0.0f,
    0.07958029955625534f, 0.16093020141124725f, 0.24611230194568634f,
    0.33791524171829224f, 0.44070982933044434f, 0.5626170039176941f,
    0.7229568362236023f, 1.0f};

typedef __attribute__((address_space(3))) void lds_t;
typedef __attribute__((address_space(1))) void gbl_t;

__device__ __forceinline__ void gload16(const void* g, void* l) {
  __builtin_amdgcn_global_load_lds((gbl_t*)g, (lds_t*)l, 16, 0, 0);
}

#define FENCE() asm volatile("" ::: "memory")

// ---------------- x f32 -> f16 ----------------
__global__ void cvt_f32_to_f16(const float* __restrict__ in,
                               _Float16* __restrict__ out, int total8) {
  int stride = gridDim.x * blockDim.x;
  for (int i = blockIdx.x * blockDim.x + threadIdx.x; i < total8; i += stride) {
    long e = (long)i * 8;
    const float4* ip = reinterpret_cast<const float4*>(in + e);
    float4 a = ip[0], b = ip[1];
    half8 o;
    o[0] = (_Float16)a.x; o[1] = (_Float16)a.y;
    o[2] = (_Float16)a.z; o[3] = (_Float16)a.w;
    o[4] = (_Float16)b.x; o[5] = (_Float16)b.y;
    o[6] = (_Float16)b.z; o[7] = (_Float16)b.w;
    *reinterpret_cast<half8*>(out + e) = o;
  }
}

// ---------------- NF4 dequant: codes[R,C] + scales[R,C/64] -> f16 [R,C] ----
__global__ void dequant_nf4(const int* __restrict__ codes,
                            const float* __restrict__ scales,
                            _Float16* __restrict__ out,
                            int total8, int C, int CB) {
  __shared__ float lut[16];
  if (threadIdx.x < 16) lut[threadIdx.x] = NF4_TAB[threadIdx.x];
  __syncthreads();
  int stride = gridDim.x * blockDim.x;
  for (int i = blockIdx.x * blockDim.x + threadIdx.x; i < total8; i += stride) {
    long e = (long)i * 8;
    int row = (int)(e / C);
    int col = (int)(e - (long)row * C);
    float sc = scales[row * CB + (col >> 6)];
    const int4* cp = reinterpret_cast<const int4*>(codes + e);
    int4 c0 = cp[0];
    int4 c1 = cp[1];
    half8 o;
    o[0] = (_Float16)(lut[c0.x & 15] * sc);
    o[1] = (_Float16)(lut[c0.y & 15] * sc);
    o[2] = (_Float16)(lut[c0.z & 15] * sc);
    o[3] = (_Float16)(lut[c0.w & 15] * sc);
    o[4] = (_Float16)(lut[c1.x & 15] * sc);
    o[5] = (_Float16)(lut[c1.y & 15] * sc);
    o[6] = (_Float16)(lut[c1.z & 15] * sc);
    o[7] = (_Float16)(lut[c1.w & 15] * sc);
    *reinterpret_cast<half8*>(out + e) = o;
  }
}

// =====================================================================
// 256x256 GEMM, BK=64, 8 waves (2Mx4N), per-wave 128x64 output.
// R7 K-loop verbatim (best known: 2303 us total). R12 changes ONLY the
// bid -> (bm,bn) mapping: RECTANGULAR PER-XCD TILE WALK.
//   x = bid & 7  (XCD, hw round-robin dispatch); j = bid >> 3 (order in XCD)
//   bm = 4x + (j & 3); bn = j >> 2
// -> each XCD owns a 4-row bm band; its ~32 concurrent blocks form a
//    4bm x 8bn rectangle: A-bytes reused by 8 blocks, B-bytes by 4, in
//    ~1.5 MB L2 window. Attacks the measured supply asymmetry: R7's
//    down-GEMM (accidental 2x16 rectangle) hits ~1700 TF with THIS SAME
//    K-loop, while gate/up (1x32 -> B streams from LLC) sit at ~860 TF.
//    (R6's bid&7=bn variant was the mirrored pathology: A streamed.)
// Double-buffered LDS (2 x 64 KB); slabs per buffer:
//   A@kk0 (0), A@kk1 (8192), B@kk0 (16384), B@kk1 (24576)  [f16 units]
// 4 phases/K-tile, 16 MFMA each; one stage slot (2 gloads) per phase:
//   P0->A0(t+1), P1->B0(t+1), P2->A1(t+1), P3->B1(t+1)
// Ledger (vmcnt, 2 loads/slot, never 0 mid-loop):
//   P1: vmcnt(4) certifies A1,B1(t); P3: vmcnt(4) certifies A0,B0(t+1).
// Chunk-XOR swizzle (phys chunk = logical ^ ((row>>1)&3)): 0 conflicts.
// EPI: 0 = f16 store; 1 = GH[idx]=silu(GH[idx])*acc (in-place); 2 = f32.
// =====================================================================
template <int K, int N, int EPI>
__global__ __launch_bounds__(512, 2) void gemm256(
    const _Float16* __restrict__ A,
    const _Float16* __restrict__ B,
    _Float16* __restrict__ GH,
    float* __restrict__ OUT) {
  constexpr int NT = K / 64;
  constexpr int NBC = N / 256;
  __shared__ __align__(16) _Float16 lds[2 * 32768];  // 128 KB

  const int t = threadIdx.x;       // 0..511
  const int lane = t & 63;
  const int wave = t >> 6;
  const int wm = wave >> 2;        // 0..1
  const int wn = wave & 3;         // 0..3

  // rectangular per-XCD walk (bijective: NBM=32=8 XCDs x 4, j<4*NBC)
  const int xcd = blockIdx.x & 7;
  const int j = blockIdx.x >> 3;
  const int bm = 4 * xcd + (j & 3);
  const int bn = j >> 2;

  // staging: round r in {0,1}: row=(t>>2)+128r, chunk lc=(t&3)^((t>>3)&3)
  const int lc = (t & 3) ^ ((t >> 3) & 3);
  const _Float16* gA = A + ((long)bm * 256 + (t >> 2)) * K + lc * 8;
  const _Float16* gB = B + ((long)bn * 256 + (t >> 2)) * K + lc * 8;
  const long rstep = (long)128 * K;
  const int dst = t * 8;  // f16 units; +4096 for round 1 (wave-linear)

  // fragment read offsets (f16 units within buffer)
  const int rA = wm * 128 + (lane & 15);
  const int rB = wn * 64 + (lane & 15);
  const int ckA = ((lane >> 4) ^ ((rA >> 1) & 3)) * 8;  // h(r+16i)==h(r)
  const int ckB = ((lane >> 4) ^ ((rB >> 1) & 3)) * 8;
  const int offA = rA * 32 + ckA;           // + i*512 (+8192 for kk1)
  const int offB = 16384 + rB * 32 + ckB;   // + j*512 (+8192 for kk1)

#define STAGE_SLOT(gp, slab, koff, dbuf)                                   \
  gload16((gp) + (koff), lds + (dbuf) * 32768 + (slab) + dst);             \
  gload16((gp) + (koff) + rstep, lds + (dbuf) * 32768 + (slab) + dst + 4096);

  // ---- prologue: stage tile 0 -> buf0, order A0,B0,A1,B1 ----
  STAGE_SLOT(gA, 0, 0, 0);
  STAGE_SLOT(gB, 16384, 0, 0);
  STAGE_SLOT(gA, 8192, 32, 0);
  STAGE_SLOT(gB, 24576, 32, 0);
  gA += 64; gB += 64;
  asm volatile("s_waitcnt vmcnt(4)" ::: "memory");  // A0,B0(0) done
  __builtin_amdgcn_s_barrier();
  FENCE();

  floatx4 acc[8][4] = {};

  for (int kt = 0; kt < NT; ++kt) {
    const int cb = kt & 1;
    const int sbuf = cb ^ 1;
    const _Float16* lb = lds + cb * 32768;
    const bool st = (kt + 1 < NT);
    const bool last = (kt == NT - 1);

    half8 a[8], b[2];

    // ---- P0: read a@kk0 x8 + b[0..1]@kk0; stage A0(t+1) ----
#pragma unroll
    for (int i = 0; i < 8; ++i)
      a[i] = *reinterpret_cast<const half8*>(&lb[offA + i * 512]);
    b[0] = *reinterpret_cast<const half8*>(&lb[offB]);
    b[1] = *reinterpret_cast<const half8*>(&lb[offB + 512]);
    if (st) { STAGE_SLOT(gA, 0, 0, sbuf); }
    __builtin_amdgcn_s_barrier();
    FENCE();
    __builtin_amdgcn_s_setprio(1);
#pragma unroll
    for (int i = 0; i < 8; ++i) {
      acc[i][0] = __builtin_amdgcn_mfma_f32_16x16x32_f16(a[i], b[0], acc[i][0], 0, 0, 0);
      acc[i][1] = __builtin_amdgcn_mfma_f32_16x16x32_f16(a[i], b[1], acc[i][1], 0, 0, 0);
    }
    __builtin_amdgcn_s_setprio(0);
    __builtin_amdgcn_s_barrier();
    FENCE();

    // ---- P1: read b[2..3]@kk0; stage B0(t+1); certify A1,B1(t) ----
    b[0] = *reinterpret_cast<const half8*>(&lb[offB + 2 * 512]);
    b[1] = *reinterpret_cast<const half8*>(&lb[offB + 3 * 512]);
    if (st) { STAGE_SLOT(gB, 16384, 0, sbuf); }
    if (last) { asm volatile("s_waitcnt vmcnt(0)" ::: "memory"); }
    else      { asm volatile("s_waitcnt vmcnt(4)" ::: "memory"); }
    __builtin_amdgcn_s_barrier();
    FENCE();
    __builtin_amdgcn_s_setprio(1);
#pragma unroll
    for (int i = 0; i < 8; ++i) {
      acc[i][2] = __builtin_amdgcn_mfma_f32_16x16x32_f16(a[i], b[0], acc[i][2], 0, 0, 0);
      acc[i][3] = __builtin_amdgcn_mfma_f32_16x16x32_f16(a[i], b[1], acc[i][3], 0, 0, 0);
    }
    __builtin_amdgcn_s_setprio(0);
    __builtin_amdgcn_s_barrier();
    FENCE();

    // ---- P2: read a@kk1 x8 + b[0..1]@kk1; stage A1(t+1) ----
#pragma unroll
    for (int i = 0; i < 8; ++i)
      a[i] = *reinterpret_cast<const half8*>(&lb[8192 + offA + i * 512]);
    b[0] = *reinterpret_cast<const half8*>(&lb[8192 + offB]);
    b[1] = *reinterpret_cast<const half8*>(&lb[8192 + offB + 512]);
    if (st) { STAGE_SLOT(gA, 8192, 32, sbuf); }
    __builtin_amdgcn_s_barrier();
    FENCE();
    __builtin_amdgcn_s_setprio(1);
#pragma unroll
    for (int i = 0; i < 8; ++i) {
      acc[i][0] = __builtin_amdgcn_mfma_f32_16x16x32_f16(a[i], b[0], acc[i][0], 0, 0, 0);
      acc[i][1] = __builtin_amdgcn_mfma_f32_16x16x32_f16(a[i], b[1], acc[i][1], 0, 0, 0);
    }
    __builtin_amdgcn_s_setprio(0);
    __builtin_amdgcn_s_barrier();
    FENCE();

    // ---- P3: read b[2..3]@kk1; stage B1(t+1); certify A0,B0(t+1) ----
    b[0] = *reinterpret_cast<const half8*>(&lb[8192 + offB + 2 * 512]);
    b[1] = *reinterpret_cast<const half8*>(&lb[8192 + offB + 3 * 512]);
    if (st) { STAGE_SLOT(gB, 24576, 32, sbuf); gA += 64; gB += 64; }
    if (!last) { asm volatile("s_waitcnt vmcnt(4)" ::: "memory"); }
    __builtin_amdgcn_s_barrier();
    FENCE();
    __builtin_amdgcn_s_setprio(1);
#pragma unroll
    for (int i = 0; i < 8; ++i) {
      acc[i][2] = __builtin_amdgcn_mfma_f32_16x16x32_f16(a[i], b[0], acc[i][2], 0, 0, 0);
      acc[i][3] = __builtin_amdgcn_mfma_f32_16x16x32_f16(a[i], b[1], acc[i][3], 0, 0, 0);
    }
    __builtin_amdgcn_s_setprio(0);
    __builtin_amdgcn_s_barrier();
    FENCE();
  }
#undef STAGE_SLOT

  // ---- epilogue ----
  const int r0 = bm * 256 + wm * 128 + (lane >> 4) * 4;
  const int c0 = bn * 256 + wn * 64 + (lane & 15);
#pragma unroll
  for (int i = 0; i < 8; ++i) {
#pragma unroll
    for (int j2 = 0; j2 < 4; ++j2) {
#pragma unroll
      for (int ii = 0; ii < 4; ++ii) {
        const long idx = (long)(r0 + i * 16 + ii) * N + (c0 + j2 * 16);
        if (EPI == 0) {
          GH[idx] = (_Float16)acc[i][j2][ii];
        } else if (EPI == 1) {
          float u = acc[i][j2][ii];
          float g = (float)GH[idx];
          GH[idx] = (_Float16)(g / (1.0f + __expf(-g)) * u);
        } else {
          OUT[idx] = acc[i][j2][ii];
        }
      }
    }
  }
}

extern "C" void kernel_launch(void* const* d_in, const int* in_sizes, int n_in,
                              void* d_out, int out_size, void* d_ws, size_t ws_size,
                              hipStream_t stream) {
  const float* x           = (const float*)d_in[0];
  const int*   gate_codes  = (const int*)d_in[1];
  const float* gate_scales = (const float*)d_in[2];
  const int*   up_codes    = (const int*)d_in[3];
  const float* up_scales   = (const float*)d_in[4];
  const int*   down_codes  = (const int*)d_in[5];
  const float* down_scales = (const float*)d_in[6];
  float* out = (float*)d_out;

  const long T = 8192, HD = 4096, M = 11008;

  // ws layout (fp16): x16 [T,HD] 67MB | W [M,HD] 90MB (reused 3x) | gh [T,M] 180MB
  char* ws = (char*)d_ws;
  _Float16* x16 = (_Float16*)ws;
  _Float16* W   = (_Float16*)(ws + T * HD * 2);
  _Float16* gh  = (_Float16*)(ws + T * HD * 2 + M * HD * 2);

  cvt_f32_to_f16<<<2048, 256, 0, stream>>>(x, x16, (int)(T * HD / 8));

  // gate: g = x @ Wg^T  -> gh (f16)
  dequant_nf4<<<2048, 256, 0, stream>>>(gate_codes, gate_scales, W,
                                        (int)(M * HD / 8), (int)HD, (int)(HD / 64));
  gemm256<4096, 11008, 0><<<(8192 / 256) * (11008 / 256), 512, 0, stream>>>(
      x16, W, gh, nullptr);

  // up + SwiGLU: gh = silu(gh) * (x @ Wu^T)   (in-place, element-exclusive)
  dequant_nf4<<<2048, 256, 0, stream>>>(up_codes, up_scales, W,
                                        (int)(M * HD / 8), (int)HD, (int)(HD / 64));
  gemm256<4096, 11008, 1><<<(8192 / 256) * (11008 / 256), 512, 0, stream>>>(
      x16, W, gh, nullptr);

  // down: out = gh @ Wd^T  (f32)
  dequant_nf4<<<2048, 256, 0, stream>>>(down_codes, down_scales, W,
                                        (int)(HD * M / 8), (int)M, (int)(M / 64));
  gemm256<11008, 4096, 2><<<(8192 / 256) * (4096 / 256), 512, 0, stream>>>(
      gh, W, nullptr, out);
}

// Round 13
// 2230.222 us; speedup vs baseline: 1.2515x; 1.0030x over previous
//
#include <hip/hip_runtime.h>
#include <hip/hip_bf16.h>

typedef _Float16 half8 __attribute__((ext_vector_type(8)));
typedef float floatx4 __attribute__((ext_vector_type(4)));

__device__ __constant__ float NF4_TAB[16] = {
    -1.0f, -0.6961928009986877f, -0.5250730514526367f, -0.39491748809814453f,
    -0.28444138169288635f, -0.18477343022823334f, -0.09105003625154495f, 0.0f,
    0.07958029955625534f, 0.16093020141124725f, 0.24611230194568634f,
    0.33791524171829224f, 0.44070982933044434f, 0.5626170039176941f,
    0.7229568362236023f, 1.0f};

typedef __attribute__((address_space(3))) void lds_t;
typedef __attribute__((address_space(1))) void gbl_t;

__device__ __forceinline__ void gload16(const void* g, void* l) {
  __builtin_amdgcn_global_load_lds((gbl_t*)g, (lds_t*)l, 16, 0, 0);
}

#define FENCE() asm volatile("" ::: "memory")

// ---------------- x f32 -> f16 ----------------
__global__ void cvt_f32_to_f16(const float* __restrict__ in,
                               _Float16* __restrict__ out, int total8) {
  int stride = gridDim.x * blockDim.x;
  for (int i = blockIdx.x * blockDim.x + threadIdx.x; i < total8; i += stride) {
    long e = (long)i * 8;
    const float4* ip = reinterpret_cast<const float4*>(in + e);
    float4 a = ip[0], b = ip[1];
    half8 o;
    o[0] = (_Float16)a.x; o[1] = (_Float16)a.y;
    o[2] = (_Float16)a.z; o[3] = (_Float16)a.w;
    o[4] = (_Float16)b.x; o[5] = (_Float16)b.y;
    o[6] = (_Float16)b.z; o[7] = (_Float16)b.w;
    *reinterpret_cast<half8*>(out + e) = o;
  }
}

// ---------------- NF4 dequant: codes[R,C] + scales[R,C/64] -> f16 [R,C] ----
__global__ void dequant_nf4(const int* __restrict__ codes,
                            const float* __restrict__ scales,
                            _Float16* __restrict__ out,
                            int total8, int C, int CB) {
  __shared__ float lut[16];
  if (threadIdx.x < 16) lut[threadIdx.x] = NF4_TAB[threadIdx.x];
  __syncthreads();
  int stride = gridDim.x * blockDim.x;
  for (int i = blockIdx.x * blockDim.x + threadIdx.x; i < total8; i += stride) {
    long e = (long)i * 8;
    int row = (int)(e / C);
    int col = (int)(e - (long)row * C);
    float sc = scales[row * CB + (col >> 6)];
    const int4* cp = reinterpret_cast<const int4*>(codes + e);
    int4 c0 = cp[0];
    int4 c1 = cp[1];
    half8 o;
    o[0] = (_Float16)(lut[c0.x & 15] * sc);
    o[1] = (_Float16)(lut[c0.y & 15] * sc);
    o[2] = (_Float16)(lut[c0.z & 15] * sc);
    o[3] = (_Float16)(lut[c0.w & 15] * sc);
    o[4] = (_Float16)(lut[c1.x & 15] * sc);
    o[5] = (_Float16)(lut[c1.y & 15] * sc);
    o[6] = (_Float16)(lut[c1.z & 15] * sc);
    o[7] = (_Float16)(lut[c1.w & 15] * sc);
    *reinterpret_cast<half8*>(out + e) = o;
  }
}

// =====================================================================
// 256x256 GEMM, BK=64, 8 waves (2Mx4N), per-wave 128x64 output.
// R12 base (best: 2237 us): R7 K-loop + rectangular per-XCD tile walk
//   (xcd=bid&7 owns bm-band [4x,4x+4); bm=4x+(j&3), bn=j>>2 -> 4x8
//   concurrent rectangle; FETCH dropped 2.6x, verified).
// R13 changes ONLY the EPI=1 epilogue: the scattered per-lane gh READ
// (4x32B segments @ 22KB row stride -> ~25% cacheline utilization,
// ~720MB effective for 180MB of g == the ~300us gap between up and
// gate) is replaced by a COALESCED LDS-staged read: after the K-loop,
// stage the block's whole 256x256 g-tile (128KB = exactly the LDS)
// via 16 rounds of global_load_lds, then read g from LDS.
// Double-buffered LDS (2 x 64 KB); slabs per buffer:
//   A@kk0 (0), A@kk1 (8192), B@kk0 (16384), B@kk1 (24576)  [f16 units]
// 4 phases/K-tile, 16 MFMA each; one stage slot (2 gloads) per phase:
//   P0->A0(t+1), P1->B0(t+1), P2->A1(t+1), P3->B1(t+1)
// Ledger (vmcnt, 2 loads/slot, never 0 mid-loop):
//   P1: vmcnt(4) certifies A1,B1(t); P3: vmcnt(4) certifies A0,B0(t+1).
// Chunk-XOR swizzle (phys chunk = logical ^ ((row>>1)&3)): 0 conflicts.
// EPI: 0 = f16 store; 1 = GH[idx]=silu(g_staged)*acc (in-place); 2 = f32.
// =====================================================================
template <int K, int N, int EPI>
__global__ __launch_bounds__(512, 2) void gemm256(
    const _Float16* __restrict__ A,
    const _Float16* __restrict__ B,
    _Float16* __restrict__ GH,
    float* __restrict__ OUT) {
  constexpr int NT = K / 64;
  constexpr int NBC = N / 256;
  __shared__ __align__(16) _Float16 lds[2 * 32768];  // 128 KB

  const int t = threadIdx.x;       // 0..511
  const int lane = t & 63;
  const int wave = t >> 6;
  const int wm = wave >> 2;        // 0..1
  const int wn = wave & 3;         // 0..3

  // rectangular per-XCD walk (bijective: NBM=32=8 XCDs x 4, j<4*NBC)
  const int xcd = blockIdx.x & 7;
  const int j = blockIdx.x >> 3;
  const int bm = 4 * xcd + (j & 3);
  const int bn = j >> 2;

  // staging: round r in {0,1}: row=(t>>2)+128r, chunk lc=(t&3)^((t>>3)&3)
  const int lc = (t & 3) ^ ((t >> 3) & 3);
  const _Float16* gA = A + ((long)bm * 256 + (t >> 2)) * K + lc * 8;
  const _Float16* gB = B + ((long)bn * 256 + (t >> 2)) * K + lc * 8;
  const long rstep = (long)128 * K;
  const int dst = t * 8;  // f16 units; +4096 for round 1 (wave-linear)

  // fragment read offsets (f16 units within buffer)
  const int rA = wm * 128 + (lane & 15);
  const int rB = wn * 64 + (lane & 15);
  const int ckA = ((lane >> 4) ^ ((rA >> 1) & 3)) * 8;  // h(r+16i)==h(r)
  const int ckB = ((lane >> 4) ^ ((rB >> 1) & 3)) * 8;
  const int offA = rA * 32 + ckA;           // + i*512 (+8192 for kk1)
  const int offB = 16384 + rB * 32 + ckB;   // + j*512 (+8192 for kk1)

#define STAGE_SLOT(gp, slab, koff, dbuf)                                   \
  gload16((gp) + (koff), lds + (dbuf) * 32768 + (slab) + dst);             \
  gload16((gp) + (koff) + rstep, lds + (dbuf) * 32768 + (slab) + dst + 4096);

  // ---- prologue: stage tile 0 -> buf0, order A0,B0,A1,B1 ----
  STAGE_SLOT(gA, 0, 0, 0);
  STAGE_SLOT(gB, 16384, 0, 0);
  STAGE_SLOT(gA, 8192, 32, 0);
  STAGE_SLOT(gB, 24576, 32, 0);
  gA += 64; gB += 64;
  asm volatile("s_waitcnt vmcnt(4)" ::: "memory");  // A0,B0(0) done
  __builtin_amdgcn_s_barrier();
  FENCE();

  floatx4 acc[8][4] = {};

  for (int kt = 0; kt < NT; ++kt) {
    const int cb = kt & 1;
    const int sbuf = cb ^ 1;
    const _Float16* lb = lds + cb * 32768;
    const bool st = (kt + 1 < NT);
    const bool last = (kt == NT - 1);

    half8 a[8], b[2];

    // ---- P0: read a@kk0 x8 + b[0..1]@kk0; stage A0(t+1) ----
#pragma unroll
    for (int i = 0; i < 8; ++i)
      a[i] = *reinterpret_cast<const half8*>(&lb[offA + i * 512]);
    b[0] = *reinterpret_cast<const half8*>(&lb[offB]);
    b[1] = *reinterpret_cast<const half8*>(&lb[offB + 512]);
    if (st) { STAGE_SLOT(gA, 0, 0, sbuf); }
    __builtin_amdgcn_s_barrier();
    FENCE();
    __builtin_amdgcn_s_setprio(1);
#pragma unroll
    for (int i = 0; i < 8; ++i) {
      acc[i][0] = __builtin_amdgcn_mfma_f32_16x16x32_f16(a[i], b[0], acc[i][0], 0, 0, 0);
      acc[i][1] = __builtin_amdgcn_mfma_f32_16x16x32_f16(a[i], b[1], acc[i][1], 0, 0, 0);
    }
    __builtin_amdgcn_s_setprio(0);
    __builtin_amdgcn_s_barrier();
    FENCE();

    // ---- P1: read b[2..3]@kk0; stage B0(t+1); certify A1,B1(t) ----
    b[0] = *reinterpret_cast<const half8*>(&lb[offB + 2 * 512]);
    b[1] = *reinterpret_cast<const half8*>(&lb[offB + 3 * 512]);
    if (st) { STAGE_SLOT(gB, 16384, 0, sbuf); }
    if (last) { asm volatile("s_waitcnt vmcnt(0)" ::: "memory"); }
    else      { asm volatile("s_waitcnt vmcnt(4)" ::: "memory"); }
    __builtin_amdgcn_s_barrier();
    FENCE();
    __builtin_amdgcn_s_setprio(1);
#pragma unroll
    for (int i = 0; i < 8; ++i) {
      acc[i][2] = __builtin_amdgcn_mfma_f32_16x16x32_f16(a[i], b[0], acc[i][2], 0, 0, 0);
      acc[i][3] = __builtin_amdgcn_mfma_f32_16x16x32_f16(a[i], b[1], acc[i][3], 0, 0, 0);
    }
    __builtin_amdgcn_s_setprio(0);
    __builtin_amdgcn_s_barrier();
    FENCE();

    // ---- P2: read a@kk1 x8 + b[0..1]@kk1; stage A1(t+1) ----
#pragma unroll
    for (int i = 0; i < 8; ++i)
      a[i] = *reinterpret_cast<const half8*>(&lb[8192 + offA + i * 512]);
    b[0] = *reinterpret_cast<const half8*>(&lb[8192 + offB]);
    b[1] = *reinterpret_cast<const half8*>(&lb[8192 + offB + 512]);
    if (st) { STAGE_SLOT(gA, 8192, 32, sbuf); }
    __builtin_amdgcn_s_barrier();
    FENCE();
    __builtin_amdgcn_s_setprio(1);
#pragma unroll
    for (int i = 0; i < 8; ++i) {
      acc[i][0] = __builtin_amdgcn_mfma_f32_16x16x32_f16(a[i], b[0], acc[i][0], 0, 0, 0);
      acc[i][1] = __builtin_amdgcn_mfma_f32_16x16x32_f16(a[i], b[1], acc[i][1], 0, 0, 0);
    }
    __builtin_amdgcn_s_setprio(0);
    __builtin_amdgcn_s_barrier();
    FENCE();

    // ---- P3: read b[2..3]@kk1; stage B1(t+1); certify A0,B0(t+1) ----
    b[0] = *reinterpret_cast<const half8*>(&lb[8192 + offB + 2 * 512]);
    b[1] = *reinterpret_cast<const half8*>(&lb[8192 + offB + 3 * 512]);
    if (st) { STAGE_SLOT(gB, 24576, 32, sbuf); gA += 64; gB += 64; }
    if (!last) { asm volatile("s_waitcnt vmcnt(4)" ::: "memory"); }
    __builtin_amdgcn_s_barrier();
    FENCE();
    __builtin_amdgcn_s_setprio(1);
#pragma unroll
    for (int i = 0; i < 8; ++i) {
      acc[i][2] = __builtin_amdgcn_mfma_f32_16x16x32_f16(a[i], b[0], acc[i][2], 0, 0, 0);
      acc[i][3] = __builtin_amdgcn_mfma_f32_16x16x32_f16(a[i], b[1], acc[i][3], 0, 0, 0);
    }
    __builtin_amdgcn_s_setprio(0);
    __builtin_amdgcn_s_barrier();
    FENCE();
  }
#undef STAGE_SLOT

  // ---- epilogue ----
  const int r0 = bm * 256 + wm * 128 + (lane >> 4) * 4;
  const int c0 = bn * 256 + wn * 64 + (lane & 15);

  if (EPI == 1) {
    // Stage this block's 256x256 g-tile into LDS with coalesced 16B
    // loads (the scattered per-lane read was ~4x cacheline waste).
    // K-loop is done; last phase ended with a barrier, LDS is dead.
    _Float16* lg = lds;  // [256][256] f16 = 128 KB = whole LDS
    const _Float16* gsrc = GH + (long)(bm * 256) * N + bn * 256;
#pragma unroll
    for (int r = 0; r < 16; ++r) {
      const int row = r * 16 + (t >> 5);
      const int col = (t & 31) * 8;
      gload16(gsrc + (long)row * N + col, lg + r * 4096 + t * 8);
    }
    asm volatile("s_waitcnt vmcnt(0)" ::: "memory");
    __builtin_amdgcn_s_barrier();
    FENCE();
    const int lr0 = wm * 128 + (lane >> 4) * 4;
    const int lc0 = wn * 64 + (lane & 15);
#pragma unroll
    for (int i = 0; i < 8; ++i) {
#pragma unroll
      for (int j2 = 0; j2 < 4; ++j2) {
#pragma unroll
        for (int ii = 0; ii < 4; ++ii) {
          const long idx = (long)(r0 + i * 16 + ii) * N + (c0 + j2 * 16);
          float u = acc[i][j2][ii];
          float g = (float)lg[(lr0 + i * 16 + ii) * 256 + (lc0 + j2 * 16)];
          GH[idx] = (_Float16)(g / (1.0f + __expf(-g)) * u);
        }
      }
    }
  } else {
#pragma unroll
    for (int i = 0; i < 8; ++i) {
#pragma unroll
      for (int j2 = 0; j2 < 4; ++j2) {
#pragma unroll
        for (int ii = 0; ii < 4; ++ii) {
          const long idx = (long)(r0 + i * 16 + ii) * N + (c0 + j2 * 16);
          if (EPI == 0) {
            GH[idx] = (_Float16)acc[i][j2][ii];
          } else {
            OUT[idx] = acc[i][j2][ii];
          }
        }
      }
    }
  }
}

extern "C" void kernel_launch(void* const* d_in, const int* in_sizes, int n_in,
                              void* d_out, int out_size, void* d_ws, size_t ws_size,
                              hipStream_t stream) {
  const float* x           = (const float*)d_in[0];
  const int*   gate_codes  = (const int*)d_in[1];
  const float* gate_scales = (const float*)d_in[2];
  const int*   up_codes    = (const int*)d_in[3];
  const float* up_scales   = (const float*)d_in[4];
  const int*   down_codes  = (const int*)d_in[5];
  const float* down_scales = (const float*)d_in[6];
  float* out = (float*)d_out;

  const long T = 8192, HD = 4096, M = 11008;

  // ws layout (fp16): x16 [T,HD] 67MB | W [M,HD] 90MB (reused 3x) | gh [T,M] 180MB
  char* ws = (char*)d_ws;
  _Float16* x16 = (_Float16*)ws;
  _Float16* W   = (_Float16*)(ws + T * HD * 2);
  _Float16* gh  = (_Float16*)(ws + T * HD * 2 + M * HD * 2);

  cvt_f32_to_f16<<<2048, 256, 0, stream>>>(x, x16, (int)(T * HD / 8));

  // gate: g = x @ Wg^T  -> gh (f16)
  dequant_nf4<<<2048, 256, 0, stream>>>(gate_codes, gate_scales, W,
                                        (int)(M * HD / 8), (int)HD, (int)(HD / 64));
  gemm256<4096, 11008, 0><<<(8192 / 256) * (11008 / 256), 512, 0, stream>>>(
      x16, W, gh, nullptr);

  // up + SwiGLU: gh = silu(gh) * (x @ Wu^T)   (in-place, element-exclusive)
  dequant_nf4<<<2048, 256, 0, stream>>>(up_codes, up_scales, W,
                                        (int)(M * HD / 8), (int)HD, (int)(HD / 64));
  gemm256<4096, 11008, 1><<<(8192 / 256) * (11008 / 256), 512, 0, stream>>>(
      x16, W, gh, nullptr);

  // down: out = gh @ Wd^T  (f32)
  dequant_nf4<<<2048, 256, 0, stream>>>(down_codes, down_scales, W,
                                        (int)(HD * M / 8), (int)M, (int)(M / 64));
  gemm256<11008, 4096, 2><<<(8192 / 256) * (4096 / 256), 512, 0, stream>>>(
      gh, W, nullptr, out);
}

// Round 15
// 2224.866 us; speedup vs baseline: 1.2545x; 1.0024x over previous
//
#include <hip/hip_runtime.h>
#include <hip/hip_bf16.h>

typedef _Float16 half8 __attribute__((ext_vector_type(8)));
typedef float floatx4 __attribute__((ext_vector_type(4)));

__device__ __constant__ float NF4_TAB[16] = {
    -1.0f, -0.6961928009986877f, -0.5250730514526367f, -0.39491748809814453f,
    -0.28444138169288635f, -0.18477343022823334f, -0.09105003625154495f, 0.0f,
    0.07958029955625534f, 0.16093020141124725f, 0.24611230194568634f,
    0.33791524171829224f, 0.44070982933044434f, 0.5626170039176941f,
    0.7229568362236023f, 1.0f};

typedef __attribute__((address_space(3))) void lds_t;
typedef __attribute__((address_space(1))) void gbl_t;

__device__ __forceinline__ void gload16(const void* g, void* l) {
  __builtin_amdgcn_global_load_lds((gbl_t*)g, (lds_t*)l, 16, 0, 0);
}

#define FENCE() asm volatile("" ::: "memory")

// ---------------- x f32 -> f16 ----------------
__global__ void cvt_f32_to_f16(const float* __restrict__ in,
                               _Float16* __restrict__ out, int total8) {
  int stride = gridDim.x * blockDim.x;
  for (int i = blockIdx.x * blockDim.x + threadIdx.x; i < total8; i += stride) {
    long e = (long)i * 8;
    const float4* ip = reinterpret_cast<const float4*>(in + e);
    float4 a = ip[0], b = ip[1];
    half8 o;
    o[0] = (_Float16)a.x; o[1] = (_Float16)a.y;
    o[2] = (_Float16)a.z; o[3] = (_Float16)a.w;
    o[4] = (_Float16)b.x; o[5] = (_Float16)b.y;
    o[6] = (_Float16)b.z; o[7] = (_Float16)b.w;
    *reinterpret_cast<half8*>(out + e) = o;
  }
}

// ---------------- NF4 dequant: codes[R,C] + scales[R,C/64] -> f16 [R,C] ----
__global__ void dequant_nf4(const int* __restrict__ codes,
                            const float* __restrict__ scales,
                            _Float16* __restrict__ out,
                            int total8, int C, int CB) {
  __shared__ float lut[16];
  if (threadIdx.x < 16) lut[threadIdx.x] = NF4_TAB[threadIdx.x];
  __syncthreads();
  int stride = gridDim.x * blockDim.x;
  for (int i = blockIdx.x * blockDim.x + threadIdx.x; i < total8; i += stride) {
    long e = (long)i * 8;
    int row = (int)(e / C);
    int col = (int)(e - (long)row * C);
    float sc = scales[row * CB + (col >> 6)];
    const int4* cp = reinterpret_cast<const int4*>(codes + e);
    int4 c0 = cp[0];
    int4 c1 = cp[1];
    half8 o;
    o[0] = (_Float16)(lut[c0.x & 15] * sc);
    o[1] = (_Float16)(lut[c0.y & 15] * sc);
    o[2] = (_Float16)(lut[c0.z & 15] * sc);
    o[3] = (_Float16)(lut[c0.w & 15] * sc);
    o[4] = (_Float16)(lut[c1.x & 15] * sc);
    o[5] = (_Float16)(lut[c1.y & 15] * sc);
    o[6] = (_Float16)(lut[c1.z & 15] * sc);
    o[7] = (_Float16)(lut[c1.w & 15] * sc);
    *reinterpret_cast<half8*>(out + e) = o;
  }
}

// =====================================================================
// 256x256 GEMM, BK=64, 8 waves (2Mx4N), per-wave 128x64 output.
// BANKED BEST (R13, validated through graph replay 3x in this lineage):
//  - R7 staging/ledger: 4 phases/K-tile (reads 10/2/10/2), one stage
//    slot (2 gloads) per phase: P0->A0(t+1), P1->B0(t+1), P2->A1(t+1),
//    P3->B1(t+1); counted vmcnt(4) at P1 (certifies A1,B1(t)) and P3
//    (certifies A0,B0(t+1)); never 0 mid-loop.
//  - R12 rectangular per-XCD walk: xcd=bid&7 owns bm band [4x,4x+4);
//    bm=4x+(j&3), bn=j>>2 -> 4x8 concurrent rect (FETCH -2.6x, measured).
//  - R13 EPI=1 epilogue: coalesced LDS-staged g read (scattered 2B read
//    was ~4x cacheline waste; up-GEMM -60us, measured).
// NOTE (R14 post-mortem): the balanced 8/4/8/4 phase split with B-frags
// held across phases was timing-NEUTRAL and FAILED post-timing replay
// validation (absmax 13.5) -> phase-shape family exhausted (6 variants
// within +-4%); this 10/2/10/2 structure is the validated one.
// Slabs per 64KB buffer: A@k0=0, A@k1=8192, B@k0=16384, B@k1=24576.
// Chunk-XOR swizzle (phys chunk = logical ^ ((row>>1)&3)): 0 conflicts.
// EPI: 0 = f16 store; 1 = GH[idx]=silu(g_staged)*acc (in-place); 2 = f32.
// =====================================================================
template <int K, int N, int EPI>
__global__ __launch_bounds__(512, 2) void gemm256(
    const _Float16* __restrict__ A,
    const _Float16* __restrict__ B,
    _Float16* __restrict__ GH,
    float* __restrict__ OUT) {
  constexpr int NT = K / 64;
  constexpr int NBC = N / 256;
  __shared__ __align__(16) _Float16 lds[2 * 32768];  // 128 KB

  const int t = threadIdx.x;       // 0..511
  const int lane = t & 63;
  const int wave = t >> 6;
  const int wm = wave >> 2;        // 0..1
  const int wn = wave & 3;         // 0..3

  // rectangular per-XCD walk (bijective: NBM=32=8 XCDs x 4, j<4*NBC)
  const int xcd = blockIdx.x & 7;
  const int j = blockIdx.x >> 3;
  const int bm = 4 * xcd + (j & 3);
  const int bn = j >> 2;

  // staging: round r in {0,1}: row=(t>>2)+128r, chunk lc=(t&3)^((t>>3)&3)
  const int lc = (t & 3) ^ ((t >> 3) & 3);
  const _Float16* gA = A + ((long)bm * 256 + (t >> 2)) * K + lc * 8;
  const _Float16* gB = B + ((long)bn * 256 + (t >> 2)) * K + lc * 8;
  const long rstep = (long)128 * K;
  const int dst = t * 8;  // f16 units; +4096 for round 1 (wave-linear)

  // fragment read offsets (f16 units within buffer)
  const int rA = wm * 128 + (lane & 15);
  const int rB = wn * 64 + (lane & 15);
  const int ckA = ((lane >> 4) ^ ((rA >> 1) & 3)) * 8;  // h(r+16i)==h(r)
  const int ckB = ((lane >> 4) ^ ((rB >> 1) & 3)) * 8;
  const int offA = rA * 32 + ckA;           // + i*512 (+8192 for kk1)
  const int offB = 16384 + rB * 32 + ckB;   // + j*512 (+8192 for kk1)

#define STAGE_SLOT(gp, slab, koff, dbuf)                                   \
  gload16((gp) + (koff), lds + (dbuf) * 32768 + (slab) + dst);             \
  gload16((gp) + (koff) + rstep, lds + (dbuf) * 32768 + (slab) + dst + 4096);

  // ---- prologue: stage tile 0 -> buf0, order A0,B0,A1,B1 ----
  STAGE_SLOT(gA, 0, 0, 0);
  STAGE_SLOT(gB, 16384, 0, 0);
  STAGE_SLOT(gA, 8192, 32, 0);
  STAGE_SLOT(gB, 24576, 32, 0);
  gA += 64; gB += 64;
  asm volatile("s_waitcnt vmcnt(4)" ::: "memory");  // A0,B0(0) done
  __builtin_amdgcn_s_barrier();
  FENCE();

  floatx4 acc[8][4] = {};

  for (int kt = 0; kt < NT; ++kt) {
    const int cb = kt & 1;
    const int sbuf = cb ^ 1;
    const _Float16* lb = lds + cb * 32768;
    const bool st = (kt + 1 < NT);
    const bool last = (kt == NT - 1);

    half8 a[8], b[2];

    // ---- P0: read a@kk0 x8 + b[0..1]@kk0; stage A0(t+1) ----
#pragma unroll
    for (int i = 0; i < 8; ++i)
      a[i] = *reinterpret_cast<const half8*>(&lb[offA + i * 512]);
    b[0] = *reinterpret_cast<const half8*>(&lb[offB]);
    b[1] = *reinterpret_cast<const half8*>(&lb[offB + 512]);
    if (st) { STAGE_SLOT(gA, 0, 0, sbuf); }
    __builtin_amdgcn_s_barrier();
    FENCE();
    __builtin_amdgcn_s_setprio(1);
#pragma unroll
    for (int i = 0; i < 8; ++i) {
      acc[i][0] = __builtin_amdgcn_mfma_f32_16x16x32_f16(a[i], b[0], acc[i][0], 0, 0, 0);
      acc[i][1] = __builtin_amdgcn_mfma_f32_16x16x32_f16(a[i], b[1], acc[i][1], 0, 0, 0);
    }
    __builtin_amdgcn_s_setprio(0);
    __builtin_amdgcn_s_barrier();
    FENCE();

    // ---- P1: read b[2..3]@kk0; stage B0(t+1); certify A1,B1(t) ----
    b[0] = *reinterpret_cast<const half8*>(&lb[offB + 2 * 512]);
    b[1] = *reinterpret_cast<const half8*>(&lb[offB + 3 * 512]);
    if (st) { STAGE_SLOT(gB, 16384, 0, sbuf); }
    if (last) { asm volatile("s_waitcnt vmcnt(0)" ::: "memory"); }
    else      { asm volatile("s_waitcnt vmcnt(4)" ::: "memory"); }
    __builtin_amdgcn_s_barrier();
    FENCE();
    __builtin_amdgcn_s_setprio(1);
#pragma unroll
    for (int i = 0; i < 8; ++i) {
      acc[i][2] = __builtin_amdgcn_mfma_f32_16x16x32_f16(a[i], b[0], acc[i][2], 0, 0, 0);
      acc[i][3] = __builtin_amdgcn_mfma_f32_16x16x32_f16(a[i], b[1], acc[i][3], 0, 0, 0);
    }
    __builtin_amdgcn_s_setprio(0);
    __builtin_amdgcn_s_barrier();
    FENCE();

    // ---- P2: read a@kk1 x8 + b[0..1]@kk1; stage A1(t+1) ----
#pragma unroll
    for (int i = 0; i < 8; ++i)
      a[i] = *reinterpret_cast<const half8*>(&lb[8192 + offA + i * 512]);
    b[0] = *reinterpret_cast<const half8*>(&lb[8192 + offB]);
    b[1] = *reinterpret_cast<const half8*>(&lb[8192 + offB + 512]);
    if (st) { STAGE_SLOT(gA, 8192, 32, sbuf); }
    __builtin_amdgcn_s_barrier();
    FENCE();
    __builtin_amdgcn_s_setprio(1);
#pragma unroll
    for (int i = 0; i < 8; ++i) {
      acc[i][0] = __builtin_amdgcn_mfma_f32_16x16x32_f16(a[i], b[0], acc[i][0], 0, 0, 0);
      acc[i][1] = __builtin_amdgcn_mfma_f32_16x16x32_f16(a[i], b[1], acc[i][1], 0, 0, 0);
    }
    __builtin_amdgcn_s_setprio(0);
    __builtin_amdgcn_s_barrier();
    FENCE();

    // ---- P3: read b[2..3]@kk1; stage B1(t+1); certify A0,B0(t+1) ----
    b[0] = *reinterpret_cast<const half8*>(&lb[8192 + offB + 2 * 512]);
    b[1] = *reinterpret_cast<const half8*>(&lb[8192 + offB + 3 * 512]);
    if (st) { STAGE_SLOT(gB, 24576, 32, sbuf); gA += 64; gB += 64; }
    if (!last) { asm volatile("s_waitcnt vmcnt(4)" ::: "memory"); }
    __builtin_amdgcn_s_barrier();
    FENCE();
    __builtin_amdgcn_s_setprio(1);
#pragma unroll
    for (int i = 0; i < 8; ++i) {
      acc[i][2] = __builtin_amdgcn_mfma_f32_16x16x32_f16(a[i], b[0], acc[i][2], 0, 0, 0);
      acc[i][3] = __builtin_amdgcn_mfma_f32_16x16x32_f16(a[i], b[1], acc[i][3], 0, 0, 0);
    }
    __builtin_amdgcn_s_setprio(0);
    __builtin_amdgcn_s_barrier();
    FENCE();
  }
#undef STAGE_SLOT

  // ---- epilogue ----
  const int r0 = bm * 256 + wm * 128 + (lane >> 4) * 4;
  const int c0 = bn * 256 + wn * 64 + (lane & 15);

  if (EPI == 1) {
    // Coalesced LDS-staged g read (scattered read was ~4x line waste)
    _Float16* lg = lds;  // [256][256] f16 = 128 KB = whole LDS
    const _Float16* gsrc = GH + (long)(bm * 256) * N + bn * 256;
#pragma unroll
    for (int r = 0; r < 16; ++r) {
      const int row = r * 16 + (t >> 5);
      const int col = (t & 31) * 8;
      gload16(gsrc + (long)row * N + col, lg + r * 4096 + t * 8);
    }
    asm volatile("s_waitcnt vmcnt(0)" ::: "memory");
    __builtin_amdgcn_s_barrier();
    FENCE();
    const int lr0 = wm * 128 + (lane >> 4) * 4;
    const int lc0 = wn * 64 + (lane & 15);
#pragma unroll
    for (int i = 0; i < 8; ++i) {
#pragma unroll
      for (int j2 = 0; j2 < 4; ++j2) {
#pragma unroll
        for (int ii = 0; ii < 4; ++ii) {
          const long idx = (long)(r0 + i * 16 + ii) * N + (c0 + j2 * 16);
          float u = acc[i][j2][ii];
          float g = (float)lg[(lr0 + i * 16 + ii) * 256 + (lc0 + j2 * 16)];
          GH[idx] = (_Float16)(g / (1.0f + __expf(-g)) * u);
        }
      }
    }
  } else {
#pragma unroll
    for (int i = 0; i < 8; ++i) {
#pragma unroll
      for (int j2 = 0; j2 < 4; ++j2) {
#pragma unroll
        for (int ii = 0; ii < 4; ++ii) {
          const long idx = (long)(r0 + i * 16 + ii) * N + (c0 + j2 * 16);
          if (EPI == 0) {
            GH[idx] = (_Float16)acc[i][j2][ii];
          } else {
            OUT[idx] = acc[i][j2][ii];
          }
        }
      }
    }
  }
}

extern "C" void kernel_launch(void* const* d_in, const int* in_sizes, int n_in,
                              void* d_out, int out_size, void* d_ws, size_t ws_size,
                              hipStream_t stream) {
  const float* x           = (const float*)d_in[0];
  const int*   gate_codes  = (const int*)d_in[1];
  const float* gate_scales = (const float*)d_in[2];
  const int*   up_codes    = (const int*)d_in[3];
  const float* up_scales   = (const float*)d_in[4];
  const int*   down_codes  = (const int*)d_in[5];
  const float* down_scales = (const float*)d_in[6];
  float* out = (float*)d_out;

  const long T = 8192, HD = 4096, M = 11008;

  // ws layout (fp16): x16 [T,HD] 67MB | W [M,HD] 90MB (reused 3x) | gh [T,M] 180MB
  char* ws = (char*)d_ws;
  _Float16* x16 = (_Float16*)ws;
  _Float16* W   = (_Float16*)(ws + T * HD * 2);
  _Float16* gh  = (_Float16*)(ws + T * HD * 2 + M * HD * 2);

  cvt_f32_to_f16<<<2048, 256, 0, stream>>>(x, x16, (int)(T * HD / 8));

  // gate: g = x @ Wg^T  -> gh (f16)
  dequant_nf4<<<2048, 256, 0, stream>>>(gate_codes, gate_scales, W,
                                        (int)(M * HD / 8), (int)HD, (int)(HD / 64));
  gemm256<4096, 11008, 0><<<(8192 / 256) * (11008 / 256), 512, 0, stream>>>(
      x16, W, gh, nullptr);

  // up + SwiGLU: gh = silu(gh) * (x @ Wu^T)   (in-place, element-exclusive)
  dequant_nf4<<<2048, 256, 0, stream>>>(up_codes, up_scales, W,
                                        (int)(M * HD / 8), (int)HD, (int)(HD / 64));
  gemm256<4096, 11008, 1><<<(8192 / 256) * (11008 / 256), 512, 0, stream>>>(
      x16, W, gh, nullptr);

  // down: out = gh @ Wd^T  (f32)
  dequant_nf4<<<2048, 256, 0, stream>>>(down_codes, down_scales, W,
                                        (int)(HD * M / 8), (int)M, (int)(M / 64));
  gemm256<11008, 4096, 2><<<(8192 / 256) * (4096 / 256), 512, 0, stream>>>(
      gh, W, nullptr, out);
}